// Round 4
// baseline (471.107 us; speedup 1.0000x reference)
//
#include <hip/hip_runtime.h>
#include <stdint.h>

typedef int int32x4 __attribute__((ext_vector_type(4)));

#define M_ROWS 8192
#define K_DIM  4096
#define N_DIM  4096

#define GPTR(p) ((const __attribute__((address_space(1))) unsigned int*)(p))
#define LPTR(p) ((__attribute__((address_space(3))) unsigned int*)(p))

// ---------- wave-level absmax: butterfly, all 64 lanes get the result ----------
__device__ __forceinline__ float wave_absmax(float m) {
#pragma unroll
  for (int off = 32; off > 0; off >>= 1)
    m = fmaxf(m, __shfl_xor(m, off, 64));
  return m;
}

// ---------- 1. quantize x -> int8 + scale. ONE WAVE PER ROW: no barriers,
// no LDS, 16 independent float4 loads in flight per lane. ----------
__global__ void quant_x_kernel(const float* __restrict__ x,
                               int8_t* __restrict__ qx,
                               float* __restrict__ sx) {
  const int wid = threadIdx.x >> 6;
  const int l = threadIdx.x & 63;
  const int row = blockIdx.x * 4 + wid;
  const float4* xr = (const float4*)(x + (size_t)row * K_DIM);
  float4 v[16];
  float m = 0.0f;
#pragma unroll
  for (int i = 0; i < 16; ++i) {
    v[i] = xr[i * 64 + l];  // 64 lanes x 16 B contiguous per instruction
    m = fmaxf(m, fmaxf(fmaxf(fabsf(v[i].x), fabsf(v[i].y)),
                       fmaxf(fabsf(v[i].z), fabsf(v[i].w))));
  }
  m = wave_absmax(m);
  float scale = m / 127.0f;
  float inv;
  if (scale == 0.0f) { scale = 1.0f; inv = 1.0f; }
  else inv = 1.0f / scale;
  if (l == 0) sx[row] = scale;
  int* qw = (int*)(qx + (size_t)row * K_DIM);
#pragma unroll
  for (int i = 0; i < 16; ++i) {
    float a = fminf(fmaxf(v[i].x * inv, -127.0f), 127.0f);
    float b = fminf(fmaxf(v[i].y * inv, -127.0f), 127.0f);
    float c = fminf(fmaxf(v[i].z * inv, -127.0f), 127.0f);
    float d = fminf(fmaxf(v[i].w * inv, -127.0f), 127.0f);
    int qa = (int)rintf(a), qb = (int)rintf(b), qc = (int)rintf(c), qd = (int)rintf(d);
    qw[i * 64 + l] =  // 64 lanes x 4 B contiguous: coalesced
        (qa & 255) | ((qb & 255) << 8) | ((qc & 255) << 16) | ((qd & 255) << 24);
  }
}

// ---------- 2. per-column partial absmax of kernel + bias int16 fake-quant
// (bias handled by the one extra block at blockIdx.y==32) ----------
__global__ void colmax_kernel(const float* __restrict__ k,
                              float* __restrict__ cmp,
                              const float* __restrict__ bias,
                              float* __restrict__ bq) {
  const int t = threadIdx.x;
  if (blockIdx.y == 32) {
    if (blockIdx.x != 0) return;
    // bias: whole-vector absmax, int16 fake-quant
    float4 v[4];
    float m = 0.0f;
#pragma unroll
    for (int i = 0; i < 4; ++i) {
      v[i] = *(const float4*)(bias + i * 1024 + t * 4);
      m = fmaxf(m, fmaxf(fmaxf(fabsf(v[i].x), fabsf(v[i].y)),
                         fmaxf(fabsf(v[i].z), fabsf(v[i].w))));
    }
    __shared__ float red[4];
#pragma unroll
    for (int off = 32; off > 0; off >>= 1)
      m = fmaxf(m, __shfl_xor(m, off, 64));
    if ((t & 63) == 0) red[t >> 6] = m;
    __syncthreads();
    float amax = fmaxf(fmaxf(red[0], red[1]), fmaxf(red[2], red[3]));
    float s = amax / 32767.0f;
    float inv;
    if (s == 0.0f) { s = 1.0f; inv = 1.0f; }
    else inv = 1.0f / s;
#pragma unroll
    for (int i = 0; i < 4; ++i) {
      float4 o;
      o.x = rintf(fminf(fmaxf(v[i].x * inv, -32767.0f), 32767.0f)) * s;
      o.y = rintf(fminf(fmaxf(v[i].y * inv, -32767.0f), 32767.0f)) * s;
      o.z = rintf(fminf(fmaxf(v[i].z * inv, -32767.0f), 32767.0f)) * s;
      o.w = rintf(fminf(fmaxf(v[i].w * inv, -32767.0f), 32767.0f)) * s;
      *(float4*)(bq + i * 1024 + t * 4) = o;
    }
    return;
  }
  const int c = blockIdx.x * 256 + t;
  const int r0 = blockIdx.y * 128;
  float m = 0.0f;
  for (int i = 0; i < 128; ++i)
    m = fmaxf(m, fabsf(k[(size_t)(r0 + i) * N_DIM + c]));
  cmp[(size_t)blockIdx.y * N_DIM + c] = m;  // partials, reduced in quant_kT
}

// ---------- 3. quantize kernel per-col and transpose -> qkT[F][D] int8.
// Per-column scale computed locally from cmp partials (finalize absorbed);
// blockIdx.y==0 blocks publish sk for the gemm epilogue. ----------
__global__ void quant_kT_kernel(const float* __restrict__ kern,
                                const float* __restrict__ cmp,
                                float* __restrict__ sk,
                                int8_t* __restrict__ qkT) {
  __shared__ int8_t tile[64][80];
  __shared__ float rsks[64];
  const int t = threadIdx.x;
  const int c0 = blockIdx.x * 64;
  const int r0 = blockIdx.y * 64;
  if (t < 64) {
    float m = 0.0f;
#pragma unroll
    for (int i = 0; i < 32; ++i) m = fmaxf(m, cmp[(size_t)i * N_DIM + c0 + t]);
    float s = m / 127.0f;
    float r;
    if (s == 0.0f) { s = 1.0f; r = 1.0f; }
    else r = 1.0f / s;
    rsks[t] = r;
    if (blockIdx.y == 0) sk[c0 + t] = s;
  }
  __syncthreads();
  const int colg = (t & 15) * 4;
  const int row = t >> 4;
  float r4[4];
#pragma unroll
  for (int j = 0; j < 4; ++j) r4[j] = rsks[colg + j];
#pragma unroll
  for (int i = 0; i < 4; ++i) {
    const int r = row + i * 16;
    float4 v = *(const float4*)&kern[(size_t)(r0 + r) * N_DIM + c0 + colg];
    tile[colg + 0][r] = (int8_t)rintf(fminf(fmaxf(v.x * r4[0], -127.0f), 127.0f));
    tile[colg + 1][r] = (int8_t)rintf(fminf(fmaxf(v.y * r4[1], -127.0f), 127.0f));
    tile[colg + 2][r] = (int8_t)rintf(fminf(fmaxf(v.z * r4[2], -127.0f), 127.0f));
    tile[colg + 3][r] = (int8_t)rintf(fminf(fmaxf(v.w * r4[3], -127.0f), 127.0f));
  }
  __syncthreads();
  const int f = t >> 2;
  const int seg = (t & 3) * 16;
  int4 w = *(const int4*)&tile[f][seg];
  *(int4*)(qkT + (size_t)(c0 + f) * K_DIM + r0 + seg) = w;
}

// ---------- 4. int8 GEMM 8192x4096x4096 + scale/bias epilogue ----------
// Round-0 proven version, byte-for-byte: 128x128x128 tile, 16x16x64 MFMA,
// chunk^(row&7) swizzle (measured 0 bank conflicts), width-16 DMA staging,
// 2 barriers/K-step. 134.5 us / MfmaUtil 49% / conflicts 0 measured.
#define BM 128
#define BN 128
#define BK 128

__global__ void gemm_kernel(const int8_t* __restrict__ qx,
                            const int8_t* __restrict__ qkT,
                            const float* __restrict__ sx,
                            const float* __restrict__ sk,
                            const float* __restrict__ bq,
                            float* __restrict__ out) {
  __shared__ int32x4 AsV[1024];  // 16 KiB: A tile [128 rows][128 bytes]
  __shared__ int32x4 BsV[1024];  // 16 KiB: B tile [128 cols][128 bytes]
  char* As = (char*)AsV;
  char* Bs = (char*)BsV;

  const int t = threadIdx.x;
  const int w = t >> 6;
  const int l = t & 63;
  const int wm = w >> 1, wn = w & 1;
  const int rowBase = blockIdx.y * BM;
  const int colBase = blockIdx.x * BN;

  const int8_t* gA = qx  + (size_t)(rowBase + (l >> 3)) * K_DIM
                         + (((l & 7) ^ (l >> 3)) * 16);
  const int8_t* gB = qkT + (size_t)(colBase + (l >> 3)) * K_DIM
                         + (((l & 7) ^ (l >> 3)) * 16);

  int arow[4], brow[4], soff[2];
#pragma unroll
  for (int mt = 0; mt < 4; ++mt)
    arow[mt] = (wm * 64 + mt * 16 + (l & 15)) * 128;
#pragma unroll
  for (int nt = 0; nt < 4; ++nt)
    brow[nt] = (wn * 64 + nt * 16 + (l & 15)) * 128;
#pragma unroll
  for (int s = 0; s < 2; ++s)
    soff[s] = ((s * 4 + (l >> 4)) ^ (l & 7)) * 16;

  int32x4 zero = {0, 0, 0, 0};
  int32x4 acc[4][4];
#pragma unroll
  for (int mt = 0; mt < 4; ++mt)
#pragma unroll
    for (int nt = 0; nt < 4; ++nt) acc[mt][nt] = zero;

  for (int k0 = 0; k0 < K_DIM; k0 += BK) {
    __syncthreads();  // previous iter's LDS reads done
#pragma unroll
    for (int j = 0; j < 4; ++j) {
      const int ca = j * 4 + w;  // 16 chunks of 8 rows x 128 B
      __builtin_amdgcn_global_load_lds(
          GPTR(gA + (size_t)ca * 8 * K_DIM + k0),
          LPTR(As + ca * 1024), 16, 0, 0);
      __builtin_amdgcn_global_load_lds(
          GPTR(gB + (size_t)ca * 8 * K_DIM + k0),
          LPTR(Bs + ca * 1024), 16, 0, 0);
    }
    __syncthreads();  // drain vmcnt(0) before reads

#pragma unroll
    for (int s = 0; s < 2; ++s) {
      int32x4 af[4], bf[4];
#pragma unroll
      for (int mt = 0; mt < 4; ++mt)
        af[mt] = *(const int32x4*)(As + arow[mt] + soff[s]);
#pragma unroll
      for (int nt = 0; nt < 4; ++nt)
        bf[nt] = *(const int32x4*)(Bs + brow[nt] + soff[s]);
#pragma unroll
      for (int mt = 0; mt < 4; ++mt)
#pragma unroll
        for (int nt = 0; nt < 4; ++nt)
          acc[mt][nt] = __builtin_amdgcn_mfma_i32_16x16x64_i8(
              af[mt], bf[nt], acc[mt][nt], 0, 0, 0);
    }
  }

  // epilogue: y = acc * sx[row] * sk[col] + bq[col]   (fp32 to d_out)
  const int lr = (l >> 4) * 4;
  const int lc = l & 15;
#pragma unroll
  for (int mt = 0; mt < 4; ++mt) {
    const int r0 = rowBase + wm * 64 + mt * 16 + lr;
    float sxr[4];
#pragma unroll
    for (int r = 0; r < 4; ++r) sxr[r] = sx[r0 + r];
#pragma unroll
    for (int nt = 0; nt < 4; ++nt) {
      const int c = colBase + wn * 64 + nt * 16 + lc;
      const float skc = sk[c];
      const float bqc = bq[c];
#pragma unroll
      for (int r = 0; r < 4; ++r)
        out[(size_t)(r0 + r) * N_DIM + c] =
            (float)acc[mt][nt][r] * (sxr[r] * skc) + bqc;
    }
  }
}

// ---------- 5. per-row int8 requant of output. ONE WAVE PER ROW, in place,
// no barriers, values cached in registers between max and rescale. ----------
__global__ void requant_kernel(float* __restrict__ y) {
  const int wid = threadIdx.x >> 6;
  const int l = threadIdx.x & 63;
  const int row = blockIdx.x * 4 + wid;
  float4* yr = (float4*)(y + (size_t)row * N_DIM);
  float4 v[16];
  float m = 0.0f;
#pragma unroll
  for (int i = 0; i < 16; ++i) {
    v[i] = yr[i * 64 + l];
    m = fmaxf(m, fmaxf(fmaxf(fabsf(v[i].x), fabsf(v[i].y)),
                       fmaxf(fabsf(v[i].z), fabsf(v[i].w))));
  }
  m = wave_absmax(m);
  float s = m / 127.0f;
  float inv;
  if (s == 0.0f) { s = 1.0f; inv = 1.0f; }
  else inv = 1.0f / s;
#pragma unroll
  for (int i = 0; i < 16; ++i) {
    float4 o;
    o.x = rintf(fminf(fmaxf(v[i].x * inv, -127.0f), 127.0f)) * s;
    o.y = rintf(fminf(fmaxf(v[i].y * inv, -127.0f), 127.0f)) * s;
    o.z = rintf(fminf(fmaxf(v[i].z * inv, -127.0f), 127.0f)) * s;
    o.w = rintf(fminf(fmaxf(v[i].w * inv, -127.0f), 127.0f)) * s;
    yr[i * 64 + l] = o;
  }
}

extern "C" void kernel_launch(void* const* d_in, const int* in_sizes, int n_in,
                              void* d_out, int out_size, void* d_ws, size_t ws_size,
                              hipStream_t stream) {
  (void)in_sizes; (void)n_in; (void)out_size; (void)ws_size;
  const float* x    = (const float*)d_in[0];
  const float* kern = (const float*)d_in[1];
  const float* bias = (const float*)d_in[2];
  float* out = (float*)d_out;

  char* w8 = (char*)d_ws;
  int8_t* qx  = (int8_t*)w8;                       // 32 MiB
  int8_t* qkT = (int8_t*)(w8 + 33554432);          // 16 MiB
  float* sx   = (float*)(w8 + 50331648);           // 8192 f (32 KiB)
  float* sk   = (float*)(w8 + 50331648 + 32768);   // 4096 f
  float* bq   = (float*)(w8 + 50331648 + 49152);   // 4096 f
  float* cmp  = (float*)(w8 + 50331648 + 65536);   // 32x4096 f (512 KiB)

  quant_x_kernel<<<M_ROWS / 4, 256, 0, stream>>>(x, qx, sx);
  colmax_kernel<<<dim3(16, 33), 256, 0, stream>>>(kern, cmp, bias, bq);
  quant_kT_kernel<<<dim3(64, 64), 256, 0, stream>>>(kern, cmp, sk, qkT);
  gemm_kernel<<<dim3(N_DIM / BN, M_ROWS / BM), 256, 0, stream>>>(qx, qkT, sx, sk, bq, out);
  requant_kernel<<<M_ROWS / 4, 256, 0, stream>>>(out);
}